// Round 13
// baseline (720.441 us; speedup 1.0000x reference)
//
#include <hip/hip_runtime.h>
#include <hip/hip_fp16.h>

// RoutingConv: N=50000, M=32 neighbors, D=128, K=8 capsules (dd=16), A=0.9
//   u[n,k,:] = A/denom * sum_j z_j * (p_j * t_{j,k}) + x[n,:]
//
// Fused persistent kernel WITHOUT hipLaunchCooperativeKernel (round-10's coop
// launch never ran — runtime rejected it). Co-residency by construction:
// grid = 1024 blocks, __launch_bounds__(256,4) caps VGPR at 128 => worst-case
// capacity 4 blocks/CU * 256 CU = 1024 => all blocks resident => hand-rolled
// grid barrier is deadlock-free. Barrier = release fetch_add + acquire spin
// at AGENT scope (acquire invalidates L1/L2 -> cross-XCD visibility of xh).
// Counters zeroed per call via hipMemsetAsync (capture-safe).
// Phase B uses per-wave dynamic tickets (atomic queue) to avoid the ~4us
// static-imbalance tail a persistent grid would have. Output stores are
// non-temporal (via clang ext_vector float4 — HIP's float4 class is rejected
// by the builtin) so 25MB of writes don't evict gather-table lines from L2.
//
// Phase-B layout: one wave per node; lane = 16g+s (g=0..3, s=0..15). Group g
// owns neighbors j=4i+g; lane holds dims 8s..8s+7. Logit/capsule partials via
// fdot2 on packed fp16; logit fold -> distributed e -> ONE exp/lane.
// neighbors = randint(0,N) exclusive-upper: clamp is memory-safety only.

#define N_NODES 50000
#define M_NBR   32
#define D_DIM   128
#define A_COEF  0.9f
#define GRID_BLKS 1024
#define CNT_OFF   12800000   // counters live after the 12.8MB xh table

typedef _Float16 h2 __attribute__((ext_vector_type(2)));
typedef float    f4 __attribute__((ext_vector_type(4)));   // for nontemporal st

__device__ __forceinline__ h2 as_h2(unsigned u) {
    union { unsigned u; h2 h; } c; c.u = u; return c.h;
}

// One fold stage: NIN values/lane -> NIN/2, summed over lane-pairs (l, l^MASK).
template<int MASK, int NIN>
__device__ __forceinline__ void fold_stage(const float* in, float* out, int lane) {
    const bool hi = (lane & MASK) != 0;
    #pragma unroll
    for (int i = 0; i < NIN / 2; ++i) {
        const float a = in[2 * i], b = in[2 * i + 1];
        const float send = hi ? a : b;
        const float recv = __shfl_xor(send, MASK);
        out[i] = (hi ? b : a) + recv;
    }
}

__global__ __launch_bounds__(256, 4) void routing_fused_kernel(
    const float*  __restrict__ x,
    const int*    __restrict__ nbr,
    __half*       __restrict__ xh,
    const float*  __restrict__ att,
    float*        __restrict__ out,
    unsigned*     bar,
    unsigned*     ticket)
{
    // ================= phase A: xh = (half)x, grid-stride =================
    {
        const float4* x4 = reinterpret_cast<const float4*>(x);
        ushort4* xh4 = reinterpret_cast<ushort4*>(xh);
        const int nitems = N_NODES * D_DIM / 4;          // 1.6M float4-groups
        for (int i = blockIdx.x * 256 + threadIdx.x; i < nitems;
             i += GRID_BLKS * 256) {
            const float4 v = x4[i];
            ushort4 h;
            h.x = __half_as_ushort(__float2half_rn(v.x));
            h.y = __half_as_ushort(__float2half_rn(v.y));
            h.z = __half_as_ushort(__float2half_rn(v.z));
            h.w = __half_as_ushort(__float2half_rn(v.w));
            xh4[i] = h;
        }
    }

    // ============ grid barrier (all GRID_BLKS blocks co-resident) ==========
    __syncthreads();
    if (threadIdx.x == 0) {
        __hip_atomic_fetch_add(bar, 1u, __ATOMIC_RELEASE, __HIP_MEMORY_SCOPE_AGENT);
        while (__hip_atomic_load(bar, __ATOMIC_ACQUIRE, __HIP_MEMORY_SCOPE_AGENT)
               < (unsigned)GRID_BLKS)
            __builtin_amdgcn_s_sleep(1);
    }
    __syncthreads();

    // ================= phase B: routing, per-wave dynamic tickets ==========
    const int lane = threadIdx.x & 63;
    const int g = lane >> 4;            // neighbor group: j = 4i + g
    const int s = lane & 15;            // owns dims 8s..8s+7
    const int gbase = lane & 0x30;

    // att_hi for this lane's 8 dims, fp16 pairs (loop-invariant)
    const float4 a0 = *reinterpret_cast<const float4*>(att + D_DIM + 8 * s);
    const float4 a1 = *reinterpret_cast<const float4*>(att + D_DIM + 8 * s + 4);
    h2 ah[4];
    ah[0] = h2{(_Float16)a0.x, (_Float16)a0.y};
    ah[1] = h2{(_Float16)a0.z, (_Float16)a0.w};
    ah[2] = h2{(_Float16)a1.x, (_Float16)a1.y};
    ah[3] = h2{(_Float16)a1.z, (_Float16)a1.w};
    const h2 ones = h2{(_Float16)1.f, (_Float16)1.f};

    for (;;) {
        int n = 0;
        if (lane == 0) n = (int)atomicAdd(ticket, 1u);   // device-scope queue
        n = __shfl(n, 0);
        if (n >= N_NODES) break;
        const int node = __builtin_amdgcn_readfirstlane(n);
        const int* nrow = nbr + node * M_NBR;

        // ---- issue ALL gathers up front ----
        uint4 zpk[8];
        #pragma unroll
        for (int i = 0; i < 8; ++i) {
            const int r = min(nrow[4 * i + g], N_NODES - 1);  // safety only
            zpk[i] = *reinterpret_cast<const uint4*>(xh + (size_t)r * D_DIM + 8 * s);
        }

        // ---- pass 1: per-neighbor partials via packed-fp16 dot2 ----
        float q[8], t_[8];
        #pragma unroll
        for (int i = 0; i < 8; ++i) {
            float qq = 0.f, zs = 0.f;
            qq = __builtin_amdgcn_fdot2(as_h2(zpk[i].x), ah[0], qq, false);
            qq = __builtin_amdgcn_fdot2(as_h2(zpk[i].y), ah[1], qq, false);
            qq = __builtin_amdgcn_fdot2(as_h2(zpk[i].z), ah[2], qq, false);
            qq = __builtin_amdgcn_fdot2(as_h2(zpk[i].w), ah[3], qq, false);
            zs = __builtin_amdgcn_fdot2(as_h2(zpk[i].x), ones, zs, false);
            zs = __builtin_amdgcn_fdot2(as_h2(zpk[i].y), ones, zs, false);
            zs = __builtin_amdgcn_fdot2(as_h2(zpk[i].z), ones, zs, false);
            zs = __builtin_amdgcn_fdot2(as_h2(zpk[i].w), ones, zs, false);
            t_[i] = zs + __shfl_xor(zs, 1);   // capsule sum (lane pair)
            q[i] = qq;
        }

        // ---- logit fold -> distributed e ----
        float f4_[4], f2_[2], f1_[1];
        fold_stage<1, 8>(q, f4_, lane);
        fold_stage<2, 4>(f4_, f2_, lane);
        fold_stage<4, 2>(f2_, f1_, lane);
        const float e = f1_[0] + __shfl_xor(f1_[0], 8);  // lane: e_{4*(s&7)+g}

        // ---- softmax: ONE exp/lane ----
        float mx = e;
        mx = fmaxf(mx, __shfl_xor(mx, 1));
        mx = fmaxf(mx, __shfl_xor(mx, 2));
        mx = fmaxf(mx, __shfl_xor(mx, 4));
        mx = fmaxf(mx, __shfl_xor(mx, 16));
        mx = fmaxf(mx, __shfl_xor(mx, 32));
        const float p = __expf(e - mx);
        float denom = p;
        denom += __shfl_xor(denom, 1);
        denom += __shfl_xor(denom, 2);
        denom += __shfl_xor(denom, 4);
        denom += __shfl_xor(denom, 16);
        denom += __shfl_xor(denom, 32);

        // ---- pass 2: weighted accumulation ----
        float acc[8] = {0.f, 0.f, 0.f, 0.f, 0.f, 0.f, 0.f, 0.f};
        #pragma unroll
        for (int i = 0; i < 8; ++i) {
            const float wi = __shfl(p, gbase | i) * t_[i];
            const h2 z01 = as_h2(zpk[i].x);
            const h2 z23 = as_h2(zpk[i].y);
            const h2 z45 = as_h2(zpk[i].z);
            const h2 z67 = as_h2(zpk[i].w);
            acc[0] = fmaf((float)z01.x, wi, acc[0]);
            acc[1] = fmaf((float)z01.y, wi, acc[1]);
            acc[2] = fmaf((float)z23.x, wi, acc[2]);
            acc[3] = fmaf((float)z23.y, wi, acc[3]);
            acc[4] = fmaf((float)z45.x, wi, acc[4]);
            acc[5] = fmaf((float)z45.y, wi, acc[5]);
            acc[6] = fmaf((float)z67.x, wi, acc[6]);
            acc[7] = fmaf((float)z67.y, wi, acc[7]);
        }

        // combine the 4 groups
        #pragma unroll
        for (int u = 0; u < 8; ++u) {
            acc[u] += __shfl_xor(acc[u], 16);
            acc[u] += __shfl_xor(acc[u], 32);
        }

        const float scale = A_COEF / denom;
        if (g == 0) {
            const uint4 xpk = *reinterpret_cast<const uint4*>(
                xh + (size_t)node * D_DIM + 8 * s);
            const h2 x01 = as_h2(xpk.x);
            const h2 x23 = as_h2(xpk.y);
            const h2 x45 = as_h2(xpk.z);
            const h2 x67 = as_h2(xpk.w);
            f4 o0, o1;
            o0.x = fmaf(scale, acc[0], (float)x01.x);
            o0.y = fmaf(scale, acc[1], (float)x01.y);
            o0.z = fmaf(scale, acc[2], (float)x23.x);
            o0.w = fmaf(scale, acc[3], (float)x23.y);
            o1.x = fmaf(scale, acc[4], (float)x45.x);
            o1.y = fmaf(scale, acc[5], (float)x45.y);
            o1.z = fmaf(scale, acc[6], (float)x67.x);
            o1.w = fmaf(scale, acc[7], (float)x67.y);
            // non-temporal: don't let 25MB of output evict gather-table lines
            __builtin_nontemporal_store(o0,
                reinterpret_cast<f4*>(out + node * D_DIM + 8 * s));
            __builtin_nontemporal_store(o1,
                reinterpret_cast<f4*>(out + node * D_DIM + 8 * s + 4));
        }
    }
}

extern "C" void kernel_launch(void* const* d_in, const int* in_sizes, int n_in,
                              void* d_out, int out_size, void* d_ws, size_t ws_size,
                              hipStream_t stream) {
    const float* x   = (const float*)d_in[0];
    const float* att = (const float*)d_in[1];
    const int*   nbr = (const int*)d_in[2];
    // d_in[3] = max_iter: unused (routing variable never feeds back into u)
    float* out = (float*)d_out;

    __half*   xh     = (__half*)d_ws;                       // 12.8 MB table
    unsigned* bar    = (unsigned*)((char*)d_ws + CNT_OFF);
    unsigned* ticket = (unsigned*)((char*)d_ws + CNT_OFF + 64);

    // zero barrier + ticket counters (capture-safe async memset)
    (void)hipMemsetAsync((char*)d_ws + CNT_OFF, 0, 128, stream);

    routing_fused_kernel<<<GRID_BLKS, 256, 0, stream>>>(
        x, nbr, xh, att, out, bar, ticket);
}

// Round 14
// 58.459 us; speedup vs baseline: 12.3239x; 12.3239x over previous
//
#include <hip/hip_runtime.h>
#include <hip/hip_fp16.h>

// RoutingConv: N=50000, M=32 neighbors, D=128, K=8 capsules (dd=16), A=0.9
//   u[n,k,:] = A/denom * sum_j z_j * (p_j * t_{j,k}) + x[n,:]
//   e_j = z_j . att[D:2D] (e_self cancels), p_j = exp(e_j - max),
//   t_{j,k} = sum_dd z_j
//
// Round-13 lesson: single-line ticket atomics serialize the GPU (720us);
// fusion's barrier+tail costs ~= the launch gap it saves. Reverted to the
// round-9 split (59.9us known-good) with two trims:
//  1) convert kernel grid-strided at 2048 blocks (was 6250 short blocks)
//  2) main kernel out-stores are NON-TEMPORAL so 25MB of write-allocate
//     doesn't evict gather-table lines from L2.
//
// Main-kernel layout: one wave per node; lane = 16g+s (g=0..3, s=0..15).
// Group g owns neighbors j=4i+g (i=0..7); lane holds dims 8s..8s+7 of its
// group's neighbor (capsule = s>>1). Logit/capsule partials via fdot2 on
// packed fp16; logit fold -> distributed e -> ONE exp/lane; residual read
// from the fp16 shadow (main kernel never touches fp32 x).
// neighbors = randint(0,N) exclusive-upper: clamp is memory-safety only.

#define N_NODES 50000
#define M_NBR   32
#define D_DIM   128
#define A_COEF  0.9f
#define CVT_BLKS 2048

typedef _Float16 h2 __attribute__((ext_vector_type(2)));
typedef float    f4 __attribute__((ext_vector_type(4)));   // for nontemporal st

__device__ __forceinline__ h2 as_h2(unsigned u) {
    union { unsigned u; h2 h; } c; c.u = u; return c.h;
}

// ---------------- precompute: xh = (half)x, grid-stride streaming ----------
__global__ __launch_bounds__(256) void to_half_kernel(
    const float4* __restrict__ x4, ushort4* __restrict__ xh4)
{
    const int nitems = N_NODES * D_DIM / 4;              // 1.6M float4-groups
    for (int i = blockIdx.x * 256 + threadIdx.x; i < nitems;
         i += CVT_BLKS * 256) {
        const float4 v = x4[i];
        ushort4 h;
        h.x = __half_as_ushort(__float2half_rn(v.x));
        h.y = __half_as_ushort(__float2half_rn(v.y));
        h.z = __half_as_ushort(__float2half_rn(v.z));
        h.w = __half_as_ushort(__float2half_rn(v.w));
        xh4[i] = h;
    }
}

// One fold stage: NIN values/lane -> NIN/2, summed over lane-pairs (l, l^MASK).
template<int MASK, int NIN>
__device__ __forceinline__ void fold_stage(const float* in, float* out, int lane) {
    const bool hi = (lane & MASK) != 0;
    #pragma unroll
    for (int i = 0; i < NIN / 2; ++i) {
        const float a = in[2 * i], b = in[2 * i + 1];
        const float send = hi ? a : b;
        const float recv = __shfl_xor(send, MASK);
        out[i] = (hi ? b : a) + recv;
    }
}

// ---------------- main ----------------
__global__ __launch_bounds__(256, 4) void routing_main_kernel(
    const int*    __restrict__ nbr,
    const __half* __restrict__ xh,
    const float*  __restrict__ att,
    float*        __restrict__ out)
{
    const int lane = threadIdx.x & 63;
    const int g = lane >> 4;            // neighbor group: j = 4i + g
    const int s = lane & 15;            // owns dims 8s..8s+7
    const int gbase = lane & 0x30;
    const int node = __builtin_amdgcn_readfirstlane(
        (int)blockIdx.x * 4 + (int)(threadIdx.x >> 6));

    // att_hi for this lane's 8 dims, converted to fp16 pairs (once)
    const float4 a0 = *reinterpret_cast<const float4*>(att + D_DIM + 8 * s);
    const float4 a1 = *reinterpret_cast<const float4*>(att + D_DIM + 8 * s + 4);
    h2 ah[4];
    ah[0] = h2{(_Float16)a0.x, (_Float16)a0.y};
    ah[1] = h2{(_Float16)a0.z, (_Float16)a0.w};
    ah[2] = h2{(_Float16)a1.x, (_Float16)a1.y};
    ah[3] = h2{(_Float16)a1.z, (_Float16)a1.w};
    const h2 ones = h2{(_Float16)1.f, (_Float16)1.f};

    const int* nrow = nbr + node * M_NBR;

    // ---- issue ALL gathers up front (latency overlap) ----
    uint4 zpk[8];
    #pragma unroll
    for (int i = 0; i < 8; ++i) {
        const int r = min(nrow[4 * i + g], N_NODES - 1);   // clamp: safety only
        zpk[i] = *reinterpret_cast<const uint4*>(xh + (size_t)r * D_DIM + 8 * s);
    }

    // ---- pass 1: per-neighbor partials via packed-fp16 dot2 ----
    float q[8], t_[8];
    #pragma unroll
    for (int i = 0; i < 8; ++i) {
        float qq = 0.f, zs = 0.f;
        qq = __builtin_amdgcn_fdot2(as_h2(zpk[i].x), ah[0], qq, false);
        qq = __builtin_amdgcn_fdot2(as_h2(zpk[i].y), ah[1], qq, false);
        qq = __builtin_amdgcn_fdot2(as_h2(zpk[i].z), ah[2], qq, false);
        qq = __builtin_amdgcn_fdot2(as_h2(zpk[i].w), ah[3], qq, false);
        zs = __builtin_amdgcn_fdot2(as_h2(zpk[i].x), ones, zs, false);
        zs = __builtin_amdgcn_fdot2(as_h2(zpk[i].y), ones, zs, false);
        zs = __builtin_amdgcn_fdot2(as_h2(zpk[i].z), ones, zs, false);
        zs = __builtin_amdgcn_fdot2(as_h2(zpk[i].w), ones, zs, false);
        t_[i] = zs + __shfl_xor(zs, 1);   // capsule sum (16 dims = lane pair)
        q[i] = qq;
    }

    // ---- logit reduction: fold to distributed form (8 shuffles) ----
    float f4_[4], f2_[2], f1_[1];
    fold_stage<1, 8>(q, f4_, lane);
    fold_stage<2, 4>(f4_, f2_, lane);
    fold_stage<4, 2>(f2_, f1_, lane);
    const float e = f1_[0] + __shfl_xor(f1_[0], 8);  // lane holds e_{4*(s&7)+g}

    // ---- softmax on distributed logits: ONE exp/lane ----
    float mx = e;
    mx = fmaxf(mx, __shfl_xor(mx, 1));
    mx = fmaxf(mx, __shfl_xor(mx, 2));
    mx = fmaxf(mx, __shfl_xor(mx, 4));   // covers the 8 distinct i
    mx = fmaxf(mx, __shfl_xor(mx, 16));
    mx = fmaxf(mx, __shfl_xor(mx, 32));  // covers the 4 groups
    const float p = __expf(e - mx);
    float denom = p;
    denom += __shfl_xor(denom, 1);
    denom += __shfl_xor(denom, 2);
    denom += __shfl_xor(denom, 4);
    denom += __shfl_xor(denom, 16);
    denom += __shfl_xor(denom, 32);      // full denom, every lane

    // ---- pass 2: weighted accumulation ----
    float acc[8] = {0.f, 0.f, 0.f, 0.f, 0.f, 0.f, 0.f, 0.f};
    #pragma unroll
    for (int i = 0; i < 8; ++i) {
        const float wi = __shfl(p, gbase | i) * t_[i];
        const h2 z01 = as_h2(zpk[i].x);
        const h2 z23 = as_h2(zpk[i].y);
        const h2 z45 = as_h2(zpk[i].z);
        const h2 z67 = as_h2(zpk[i].w);
        acc[0] = fmaf((float)z01.x, wi, acc[0]);
        acc[1] = fmaf((float)z01.y, wi, acc[1]);
        acc[2] = fmaf((float)z23.x, wi, acc[2]);
        acc[3] = fmaf((float)z23.y, wi, acc[3]);
        acc[4] = fmaf((float)z45.x, wi, acc[4]);
        acc[5] = fmaf((float)z45.y, wi, acc[5]);
        acc[6] = fmaf((float)z67.x, wi, acc[6]);
        acc[7] = fmaf((float)z67.y, wi, acc[7]);
    }

    // combine the 4 groups (same dims, disjoint neighbor subsets)
    #pragma unroll
    for (int u = 0; u < 8; ++u) {
        acc[u] += __shfl_xor(acc[u], 16);
        acc[u] += __shfl_xor(acc[u], 32);
    }

    const float scale = A_COEF / denom;  // softmax denom + residual coef
    if (g == 0) {
        // residual from the fp16 shadow: 16B = this lane's 8 dims
        const uint4 xpk = *reinterpret_cast<const uint4*>(
            xh + (size_t)node * D_DIM + 8 * s);
        const h2 x01 = as_h2(xpk.x);
        const h2 x23 = as_h2(xpk.y);
        const h2 x45 = as_h2(xpk.z);
        const h2 x67 = as_h2(xpk.w);
        f4 o0, o1;
        o0.x = fmaf(scale, acc[0], (float)x01.x);
        o0.y = fmaf(scale, acc[1], (float)x01.y);
        o0.z = fmaf(scale, acc[2], (float)x23.x);
        o0.w = fmaf(scale, acc[3], (float)x23.y);
        o1.x = fmaf(scale, acc[4], (float)x45.x);
        o1.y = fmaf(scale, acc[5], (float)x45.y);
        o1.z = fmaf(scale, acc[6], (float)x67.x);
        o1.w = fmaf(scale, acc[7], (float)x67.y);
        // non-temporal: don't let 25MB of output evict gather-table lines
        __builtin_nontemporal_store(o0,
            reinterpret_cast<f4*>(out + node * D_DIM + 8 * s));
        __builtin_nontemporal_store(o1,
            reinterpret_cast<f4*>(out + node * D_DIM + 8 * s + 4));
    }
}

extern "C" void kernel_launch(void* const* d_in, const int* in_sizes, int n_in,
                              void* d_out, int out_size, void* d_ws, size_t ws_size,
                              hipStream_t stream) {
    const float* x   = (const float*)d_in[0];
    const float* att = (const float*)d_in[1];
    const int*   nbr = (const int*)d_in[2];
    // d_in[3] = max_iter: unused (routing variable never feeds back into u)
    float* out = (float*)d_out;

    __half* xh = (__half*)d_ws;          // 50000*128 fp16 = 12.8 MB scratch

    to_half_kernel<<<CVT_BLKS, 256, 0, stream>>>((const float4*)x, (ushort4*)xh);

    const int grid = N_NODES / 4;        // 4 waves/block, 1 node/wave, exact
    routing_main_kernel<<<grid, 256, 0, stream>>>(nbr, xh, att, out);
}